// Round 1
// baseline (596.013 us; speedup 1.0000x reference)
//
#include <hip/hip_runtime.h>
#include <hip/hip_bf16.h>

typedef unsigned short u16;
typedef short s16x8 __attribute__((ext_vector_type(8)));
typedef float f32x4 __attribute__((ext_vector_type(4)));

#define MFMA_BF16(a, b, c) __builtin_amdgcn_mfma_f32_16x16x32_bf16((a), (b), (c), 0, 0, 0)

static constexpr int D_IN   = 64;
static constexpr int H_DIM  = 512;
static constexpr int M_TILE = 32;
static constexpr int AST    = 520;  // LDS row stride (bf16) for 512-wide bufs: bank advance 4/row
static constexpr int XST    = 72;   // LDS row stride for x tile

__device__ __forceinline__ u16 f2bf(float f) {
  unsigned u = __builtin_bit_cast(unsigned, f);
  u += 0x7fffu + ((u >> 16) & 1u);   // RNE
  return (u16)(u >> 16);
}
__device__ __forceinline__ float bfb2f(unsigned bits16) {
  return __builtin_bit_cast(float, bits16 << 16);
}
__device__ __forceinline__ float fast_tanh(float x) {
  // tanh(x) = 1 - 2/(e^{2x}+1); exact limits at +-inf via rcp(inf)=0
  float e = __expf(2.0f * x);
  return 1.0f - 2.0f * __builtin_amdgcn_rcpf(e + 1.0f);
}

// ---- prep: fp32 weights -> bf16 in both layouts (ws scratch) ----
// ws layout (bf16 elems): w0b[64*512] w0t[512*64] w1b[512*512] w1t w2b w2t  (~2.2MB)
__global__ void prep_weights(const float* __restrict__ W0,
                             const float* __restrict__ W1,
                             const float* __restrict__ W2,
                             u16* __restrict__ ws) {
  u16* w0b = ws;
  u16* w0t = w0b + D_IN * H_DIM;
  u16* w1b = w0t + D_IN * H_DIM;
  u16* w1t = w1b + H_DIM * H_DIM;
  u16* w2b = w1t + H_DIM * H_DIM;
  u16* w2t = w2b + H_DIM * H_DIM;
  int idx = blockIdx.x * 256 + threadIdx.x;   // exactly 512*512 threads
  int k = idx >> 9;
  int n = idx & 511;
  u16 v1 = f2bf(W1[idx]);
  u16 v2 = f2bf(W2[idx]);
  w1b[idx] = v1; w1t[n * 512 + k] = v1;
  w2b[idx] = v2; w2t[n * 512 + k] = v2;
  if (idx < D_IN * H_DIM) {                   // W0 is [64][512]: k=idx>>9 in [0,64)
    u16 v0 = f2bf(W0[idx]);
    w0b[idx] = v0;
    w0t[n * 64 + k] = v0;
  }
}

// 512-wide GEMM K-loop: A (M_TILE x 512 bf16) from LDS, B-frags 16B/lane from L2.
#define GEMM512(ABUF, BPTR)                                                     \
  {                                                                             \
    _Pragma("unroll") for (int mt = 0; mt < 2; ++mt)                            \
      _Pragma("unroll") for (int nt = 0; nt < 8; ++nt)                          \
        acc[mt][nt] = (f32x4){0.f, 0.f, 0.f, 0.f};                              \
    for (int kc = 0; kc < 16; ++kc) {                                           \
      s16x8 a0 = *(const s16x8*)((ABUF) + ln * AST + kc * 32 + q * 8);          \
      s16x8 a1 = *(const s16x8*)((ABUF) + (16 + ln) * AST + kc * 32 + q * 8);   \
      _Pragma("unroll")                                                         \
      for (int nt = 0; nt < 8; ++nt) {                                          \
        s16x8 b = *(const s16x8*)((BPTR) + (size_t)(nwb + nt * 16 + ln) * 512   \
                                  + kc * 32 + q * 8);                           \
        acc[0][nt] = MFMA_BF16(a0, b, acc[0][nt]);                              \
        acc[1][nt] = MFMA_BF16(a1, b, acc[1][nt]);                              \
      }                                                                         \
    }                                                                           \
  }

__global__ __launch_bounds__(256, 2) void hnn_fused(
    const float* __restrict__ x,
    const float* __restrict__ bias0,
    const float* __restrict__ bias1,
    const float* __restrict__ bias2,
    const float* __restrict__ W3,
    const u16* __restrict__ ws,
    float* __restrict__ out)
{
  const u16* w0b = ws;
  const u16* w0t = w0b + D_IN * H_DIM;
  const u16* w1b = w0t + D_IN * H_DIM;
  const u16* w1t = w1b + H_DIM * H_DIM;
  const u16* w2b = w1t + H_DIM * H_DIM;
  const u16* w2t = w2b + H_DIM * H_DIM;

  __shared__ __align__(16) u16 xs[M_TILE * XST];     // 4.5 KB
  __shared__ __align__(16) u16 bufA[M_TILE * AST];   // 32.5 KB
  __shared__ __align__(16) u16 bufB[M_TILE * AST];   // 32.5 KB -> 69.5 KB total, 2 blk/CU

  const int tid  = threadIdx.x;
  const int wave = tid >> 6;
  const int lane = tid & 63;
  const int ln   = lane & 15;   // MFMA non-k index
  const int q    = lane >> 4;   // k-quad
  const int nwb  = wave * 128;  // wave's column slice in 512-wide GEMMs
  const int row0 = blockIdx.x * M_TILE;

  // ---- stage x tile: 32x64 fp32 -> bf16 LDS ----
  {
    int e = tid * 8;
    int r = e >> 6, c = e & 63;
    const float4* src = (const float4*)(x + (size_t)(row0 + r) * D_IN + c);
    float4 f0 = src[0];
    float4 f1 = src[1];
    u16* dst = xs + r * XST + c;
    dst[0] = f2bf(f0.x); dst[1] = f2bf(f0.y); dst[2] = f2bf(f0.z); dst[3] = f2bf(f0.w);
    dst[4] = f2bf(f1.x); dst[5] = f2bf(f1.y); dst[6] = f2bf(f1.z); dst[7] = f2bf(f1.w);
  }
  __syncthreads();

  f32x4 acc[2][8];
  unsigned h0p[2][8][2];   // h0 bf16x2-packed, C-layout (for tanh' in bwd)
  unsigned h1p[2][8][2];
  float bias[8];

  // ================ GEMM0: z0 = x @ W0  (K=64) ================
  #pragma unroll
  for (int nt = 0; nt < 8; ++nt) bias[nt] = bias0[nwb + nt * 16 + ln];
  #pragma unroll
  for (int mt = 0; mt < 2; ++mt)
    #pragma unroll
    for (int nt = 0; nt < 8; ++nt) acc[mt][nt] = (f32x4){0.f, 0.f, 0.f, 0.f};
  #pragma unroll
  for (int kc = 0; kc < 2; ++kc) {
    s16x8 a0 = *(const s16x8*)(xs + ln * XST + kc * 32 + q * 8);
    s16x8 a1 = *(const s16x8*)(xs + (16 + ln) * XST + kc * 32 + q * 8);
    #pragma unroll
    for (int nt = 0; nt < 8; ++nt) {
      s16x8 b = *(const s16x8*)(w0t + (nwb + nt * 16 + ln) * 64 + kc * 32 + q * 8);
      acc[0][nt] = MFMA_BF16(a0, b, acc[0][nt]);
      acc[1][nt] = MFMA_BF16(a1, b, acc[1][nt]);
    }
  }
  // epilogue: h0 = tanh(z0+b0) -> regs + bufA
  #pragma unroll
  for (int mt = 0; mt < 2; ++mt)
    #pragma unroll
    for (int nt = 0; nt < 8; ++nt) {
      int col = nwb + nt * 16 + ln;
      u16 u[4];
      #pragma unroll
      for (int r = 0; r < 4; ++r) {
        float th = fast_tanh(acc[mt][nt][r] + bias[nt]);
        u[r] = f2bf(th);
        bufA[(mt * 16 + q * 4 + r) * AST + col] = u[r];
      }
      h0p[mt][nt][0] = (unsigned)u[0] | ((unsigned)u[1] << 16);
      h0p[mt][nt][1] = (unsigned)u[2] | ((unsigned)u[3] << 16);
    }
  __syncthreads();

  // ================ GEMM1: z1 = h0 @ W1 ================
  #pragma unroll
  for (int nt = 0; nt < 8; ++nt) bias[nt] = bias1[nwb + nt * 16 + ln];
  GEMM512(bufA, w1t);
  #pragma unroll
  for (int mt = 0; mt < 2; ++mt)
    #pragma unroll
    for (int nt = 0; nt < 8; ++nt) {
      int col = nwb + nt * 16 + ln;
      u16 u[4];
      #pragma unroll
      for (int r = 0; r < 4; ++r) {
        float th = fast_tanh(acc[mt][nt][r] + bias[nt]);
        u[r] = f2bf(th);
        bufB[(mt * 16 + q * 4 + r) * AST + col] = u[r];
      }
      h1p[mt][nt][0] = (unsigned)u[0] | ((unsigned)u[1] << 16);
      h1p[mt][nt][1] = (unsigned)u[2] | ((unsigned)u[3] << 16);
    }
  __syncthreads();

  // ================ GEMM2: z2 = h1 @ W2 ; gz2 = W3*(1-h2^2) ================
  #pragma unroll
  for (int nt = 0; nt < 8; ++nt) bias[nt] = bias2[nwb + nt * 16 + ln];
  float w3v[8];
  #pragma unroll
  for (int nt = 0; nt < 8; ++nt) w3v[nt] = W3[nwb + nt * 16 + ln];
  GEMM512(bufB, w2t);
  #pragma unroll
  for (int mt = 0; mt < 2; ++mt)
    #pragma unroll
    for (int nt = 0; nt < 8; ++nt) {
      int col = nwb + nt * 16 + ln;
      #pragma unroll
      for (int r = 0; r < 4; ++r) {
        float th = fast_tanh(acc[mt][nt][r] + bias[nt]);
        float gz = w3v[nt] * (1.0f - th * th);
        bufA[(mt * 16 + q * 4 + r) * AST + col] = f2bf(gz);
      }
    }
  __syncthreads();

  // ================ GEMM3: g1 = gz2 @ W2^T ; gz1 = g1*(1-h1^2) ================
  GEMM512(bufA, w2b);
  #pragma unroll
  for (int mt = 0; mt < 2; ++mt)
    #pragma unroll
    for (int nt = 0; nt < 8; ++nt) {
      int col = nwb + nt * 16 + ln;
      unsigned p0 = h1p[mt][nt][0], p1 = h1p[mt][nt][1];
      float hh[4] = { bfb2f(p0 & 0xffffu), bfb2f(p0 >> 16),
                      bfb2f(p1 & 0xffffu), bfb2f(p1 >> 16) };
      #pragma unroll
      for (int r = 0; r < 4; ++r) {
        float gz = acc[mt][nt][r] * (1.0f - hh[r] * hh[r]);
        bufB[(mt * 16 + q * 4 + r) * AST + col] = f2bf(gz);
      }
    }
  __syncthreads();

  // ================ GEMM4: g0 = gz1 @ W1^T ; gz0 = g0*(1-h0^2) ================
  GEMM512(bufB, w1b);
  #pragma unroll
  for (int mt = 0; mt < 2; ++mt)
    #pragma unroll
    for (int nt = 0; nt < 8; ++nt) {
      int col = nwb + nt * 16 + ln;
      unsigned p0 = h0p[mt][nt][0], p1 = h0p[mt][nt][1];
      float hh[4] = { bfb2f(p0 & 0xffffu), bfb2f(p0 >> 16),
                      bfb2f(p1 & 0xffffu), bfb2f(p1 >> 16) };
      #pragma unroll
      for (int r = 0; r < 4; ++r) {
        float gz = acc[mt][nt][r] * (1.0f - hh[r] * hh[r]);
        bufA[(mt * 16 + q * 4 + r) * AST + col] = f2bf(gz);
      }
    }
  __syncthreads();

  // ================ GEMM5: gradH = gz0 @ W0^T (32x64), symplectic store ======
  {
    f32x4 acc5[2];
    acc5[0] = (f32x4){0.f, 0.f, 0.f, 0.f};
    acc5[1] = (f32x4){0.f, 0.f, 0.f, 0.f};
    const int mt5 = wave & 1;            // row half
    const int nb5 = (wave >> 1) * 32;    // gradH column base (0 or 32)
    for (int kc = 0; kc < 16; ++kc) {
      s16x8 a = *(const s16x8*)(bufA + (mt5 * 16 + ln) * AST + kc * 32 + q * 8);
      #pragma unroll
      for (int nt = 0; nt < 2; ++nt) {
        s16x8 b = *(const s16x8*)(w0b + (size_t)(nb5 + nt * 16 + ln) * 512
                                  + kc * 32 + q * 8);
        acc5[nt] = MFMA_BF16(a, b, acc5[nt]);
      }
    }
    #pragma unroll
    for (int nt = 0; nt < 2; ++nt) {
      int g = nb5 + nt * 16 + ln;                 // gradH column
      int c = (g < 32) ? g + 32 : g - 32;         // out = concat(gradH[:,32:], -gradH[:,:32])
      float s = (g < 32) ? -1.0f : 1.0f;
      #pragma unroll
      for (int r = 0; r < 4; ++r) {
        int grow = row0 + mt5 * 16 + q * 4 + r;
        out[(size_t)grow * 64 + c] = s * acc5[nt][r];
      }
    }
  }
}

extern "C" void kernel_launch(void* const* d_in, const int* in_sizes, int n_in,
                              void* d_out, int out_size, void* d_ws, size_t ws_size,
                              hipStream_t stream) {
  // setup_inputs order: t, x, W0, b0, W1, b1, W2, b2, W3, b3
  const float* x  = (const float*)d_in[1];
  const float* W0 = (const float*)d_in[2];
  const float* b0 = (const float*)d_in[3];
  const float* W1 = (const float*)d_in[4];
  const float* b1 = (const float*)d_in[5];
  const float* W2 = (const float*)d_in[6];
  const float* b2 = (const float*)d_in[7];
  const float* W3 = (const float*)d_in[8];
  u16* ws = (u16*)d_ws;
  float* out = (float*)d_out;

  prep_weights<<<(H_DIM * H_DIM) / 256, 256, 0, stream>>>(W0, W1, W2, ws);
  hnn_fused<<<65536 / M_TILE, 256, 0, stream>>>(x, b0, b1, b2, W3, ws, out);
}

// Round 2
// 371.799 us; speedup vs baseline: 1.6031x; 1.6031x over previous
//
#include <hip/hip_runtime.h>
#include <hip/hip_bf16.h>

typedef unsigned short u16;
typedef short s16x8 __attribute__((ext_vector_type(8)));
typedef float f32x4 __attribute__((ext_vector_type(4)));

#define MFMA_BF16(a, b, c) __builtin_amdgcn_mfma_f32_16x16x32_bf16((a), (b), (c), 0, 0, 0)

static constexpr int D_IN   = 64;
static constexpr int H_DIM  = 512;
static constexpr int M_TILE = 32;
static constexpr int AST    = 520;  // LDS row stride (bf16): row-to-row bank advance 4
static constexpr int XST    = 72;   // LDS row stride for x tile

__device__ __forceinline__ u16 f2bf(float f) {
  unsigned u = __builtin_bit_cast(unsigned, f);
  u += 0x7fffu + ((u >> 16) & 1u);   // RNE
  return (u16)(u >> 16);
}
__device__ __forceinline__ float bfb2f(unsigned bits16) {
  return __builtin_bit_cast(float, bits16 << 16);
}
__device__ __forceinline__ float fast_tanh(float x) {
  float e = __expf(2.0f * x);
  return 1.0f - 2.0f * __builtin_amdgcn_rcpf(e + 1.0f);
}

// ---- prep: fp32 weights -> bf16, packed in MFMA-B-fragment order ----
// For each (ntg = 16-col tile, kc = 32-wide K chunk): 512 elems stored as
// lane*8 contiguous, lane=(q*16+ln), elem j -> B[k=kc*32+q*8+j][n=ntg*16+ln].
// A wave's B-frag load is then base + uniform + lane*16B: one contiguous 1KB.
// ws layout (bf16): p0f[64x512] p0b[512x64] p1f p1b p2f p2b  (~2.2MB)
__global__ void prep_weights(const float* __restrict__ W0,
                             const float* __restrict__ W1,
                             const float* __restrict__ W2,
                             u16* __restrict__ ws) {
  u16* p0f = ws;                       // fwd W0: K=64,  N=512
  u16* p0b = p0f + D_IN * H_DIM;       // bwd W0^T: K=512, N=64
  u16* p1f = p0b + D_IN * H_DIM;
  u16* p1b = p1f + H_DIM * H_DIM;
  u16* p2f = p1b + H_DIM * H_DIM;
  u16* p2b = p2f + H_DIM * H_DIM;

  int t = blockIdx.x * 256 + threadIdx.x;   // 32768 threads total
  int lane = t & 63;
  int kc   = (t >> 6) & 15;
  int ntg  = t >> 10;                       // 0..31
  int ln = lane & 15, q = lane >> 4;
  int n = ntg * 16 + ln;
  int k = kc * 32 + q * 8;

  #pragma unroll
  for (int j = 0; j < 8; ++j) {
    // fwd: B[k][n] = W[k][n]
    p1f[t * 8 + j] = f2bf(W1[(k + j) * 512 + n]);
    p2f[t * 8 + j] = f2bf(W2[(k + j) * 512 + n]);
    // bwd: B[k][n] = W^T[k][n] = W[n][k]
    p1b[t * 8 + j] = f2bf(W1[n * 512 + (k + j)]);
    p2b[t * 8 + j] = f2bf(W2[n * 512 + (k + j)]);
  }
  if (kc < 2) {  // W0 fwd: K=64 -> kc in {0,1}, ntg 0..31
    int t0 = (ntg * 2 + kc) * 64 + lane;
    #pragma unroll
    for (int j = 0; j < 8; ++j)
      p0f[t0 * 8 + j] = f2bf(W0[(k + j) * 512 + n]);   // W0[k][n], k<64
  }
  if (ntg < 4) { // W0 bwd: N=64 -> ntg 0..3, kc 0..15
    int t0 = (ntg * 16 + kc) * 64 + lane;
    #pragma unroll
    for (int j = 0; j < 8; ++j)
      p0b[t0 * 8 + j] = f2bf(W0[n * 512 + (k + j)]);   // W0[n][k], n<64
  }
}

// 512-wide GEMM K-loop: A (32x512 bf16) from LDS, B frag-packed from L2,
// each B load = contiguous 1KB per wave.
#define GEMM512(ABUF, BP)                                                       \
  {                                                                             \
    _Pragma("unroll") for (int mt = 0; mt < 2; ++mt)                            \
      _Pragma("unroll") for (int nt = 0; nt < 8; ++nt)                          \
        acc[mt][nt] = (f32x4){0.f, 0.f, 0.f, 0.f};                              \
    const u16* bpw = (BP) + (wave << 16) + lane * 8;                            \
    _Pragma("unroll 2")                                                         \
    for (int kc = 0; kc < 16; ++kc) {                                           \
      s16x8 a0 = *(const s16x8*)((ABUF) + ln * AST + kc * 32 + q * 8);          \
      s16x8 a1 = *(const s16x8*)((ABUF) + (16 + ln) * AST + kc * 32 + q * 8);   \
      _Pragma("unroll")                                                         \
      for (int nt = 0; nt < 8; ++nt) {                                          \
        s16x8 b = *(const s16x8*)(bpw + ((nt * 16 + kc) << 9));                 \
        acc[0][nt] = MFMA_BF16(a0, b, acc[0][nt]);                              \
        acc[1][nt] = MFMA_BF16(a1, b, acc[1][nt]);                              \
      }                                                                         \
    }                                                                           \
  }

__global__ __launch_bounds__(256, 2) void hnn_fused(
    const float* __restrict__ x,
    const float* __restrict__ bias0,
    const float* __restrict__ bias1,
    const float* __restrict__ bias2,
    const float* __restrict__ W3,
    const u16* __restrict__ ws,
    float* __restrict__ out)
{
  const u16* p0f = ws;
  const u16* p0b = p0f + D_IN * H_DIM;
  const u16* p1f = p0b + D_IN * H_DIM;
  const u16* p1b = p1f + H_DIM * H_DIM;
  const u16* p2f = p1b + H_DIM * H_DIM;
  const u16* p2b = p2f + H_DIM * H_DIM;

  __shared__ __align__(16) u16 xs[M_TILE * XST];     // 4.5 KB
  __shared__ __align__(16) u16 bufA[M_TILE * AST];   // 32.5 KB
  __shared__ __align__(16) u16 bufB[M_TILE * AST];   // 32.5 KB -> 69.5 KB, 2 blk/CU

  const int tid  = threadIdx.x;
  const int wave = tid >> 6;
  const int lane = tid & 63;
  const int ln   = lane & 15;
  const int q    = lane >> 4;
  const int nwb  = wave * 128;
  const int row0 = blockIdx.x * M_TILE;

  // ---- stage x tile: 32x64 fp32 -> bf16 LDS ----
  {
    int e = tid * 8;
    int r = e >> 6, c = e & 63;
    const float4* src = (const float4*)(x + (size_t)(row0 + r) * D_IN + c);
    float4 f0 = src[0];
    float4 f1 = src[1];
    u16* dst = xs + r * XST + c;
    dst[0] = f2bf(f0.x); dst[1] = f2bf(f0.y); dst[2] = f2bf(f0.z); dst[3] = f2bf(f0.w);
    dst[4] = f2bf(f1.x); dst[5] = f2bf(f1.y); dst[6] = f2bf(f1.z); dst[7] = f2bf(f1.w);
  }
  __syncthreads();

  f32x4 acc[2][8];
  unsigned h0p[2][8][2];   // h0 bf16x2-packed, C-layout (for tanh' in bwd)
  unsigned h1p[2][8][2];
  float bias[8];

  // ================ GEMM0: z0 = x @ W0  (K=64) ================
  #pragma unroll
  for (int nt = 0; nt < 8; ++nt) bias[nt] = bias0[nwb + nt * 16 + ln];
  #pragma unroll
  for (int mt = 0; mt < 2; ++mt)
    #pragma unroll
    for (int nt = 0; nt < 8; ++nt) acc[mt][nt] = (f32x4){0.f, 0.f, 0.f, 0.f};
  {
    const u16* bpw0 = p0f + (wave << 13) + lane * 8;   // wave*8 ntg * 2 kc * 512
    #pragma unroll
    for (int kc = 0; kc < 2; ++kc) {
      s16x8 a0 = *(const s16x8*)(xs + ln * XST + kc * 32 + q * 8);
      s16x8 a1 = *(const s16x8*)(xs + (16 + ln) * XST + kc * 32 + q * 8);
      #pragma unroll
      for (int nt = 0; nt < 8; ++nt) {
        s16x8 b = *(const s16x8*)(bpw0 + ((nt * 2 + kc) << 9));
        acc[0][nt] = MFMA_BF16(a0, b, acc[0][nt]);
        acc[1][nt] = MFMA_BF16(a1, b, acc[1][nt]);
      }
    }
  }
  #pragma unroll
  for (int mt = 0; mt < 2; ++mt)
    #pragma unroll
    for (int nt = 0; nt < 8; ++nt) {
      int col = nwb + nt * 16 + ln;
      u16 u[4];
      #pragma unroll
      for (int r = 0; r < 4; ++r) {
        float th = fast_tanh(acc[mt][nt][r] + bias[nt]);
        u[r] = f2bf(th);
        bufA[(mt * 16 + q * 4 + r) * AST + col] = u[r];
      }
      h0p[mt][nt][0] = (unsigned)u[0] | ((unsigned)u[1] << 16);
      h0p[mt][nt][1] = (unsigned)u[2] | ((unsigned)u[3] << 16);
    }
  __syncthreads();

  // ================ GEMM1: z1 = h0 @ W1 ================
  #pragma unroll
  for (int nt = 0; nt < 8; ++nt) bias[nt] = bias1[nwb + nt * 16 + ln];
  GEMM512(bufA, p1f);
  #pragma unroll
  for (int mt = 0; mt < 2; ++mt)
    #pragma unroll
    for (int nt = 0; nt < 8; ++nt) {
      int col = nwb + nt * 16 + ln;
      u16 u[4];
      #pragma unroll
      for (int r = 0; r < 4; ++r) {
        float th = fast_tanh(acc[mt][nt][r] + bias[nt]);
        u[r] = f2bf(th);
        bufB[(mt * 16 + q * 4 + r) * AST + col] = u[r];
      }
      h1p[mt][nt][0] = (unsigned)u[0] | ((unsigned)u[1] << 16);
      h1p[mt][nt][1] = (unsigned)u[2] | ((unsigned)u[3] << 16);
    }
  __syncthreads();

  // ================ GEMM2: z2 = h1 @ W2 ; gz2 = W3*(1-h2^2) ================
  #pragma unroll
  for (int nt = 0; nt < 8; ++nt) bias[nt] = bias2[nwb + nt * 16 + ln];
  float w3v[8];
  #pragma unroll
  for (int nt = 0; nt < 8; ++nt) w3v[nt] = W3[nwb + nt * 16 + ln];
  GEMM512(bufB, p2f);
  #pragma unroll
  for (int mt = 0; mt < 2; ++mt)
    #pragma unroll
    for (int nt = 0; nt < 8; ++nt) {
      int col = nwb + nt * 16 + ln;
      #pragma unroll
      for (int r = 0; r < 4; ++r) {
        float th = fast_tanh(acc[mt][nt][r] + bias[nt]);
        float gz = w3v[nt] * (1.0f - th * th);
        bufA[(mt * 16 + q * 4 + r) * AST + col] = f2bf(gz);
      }
    }
  __syncthreads();

  // ================ GEMM3: g1 = gz2 @ W2^T ; gz1 = g1*(1-h1^2) ================
  GEMM512(bufA, p2b);
  #pragma unroll
  for (int mt = 0; mt < 2; ++mt)
    #pragma unroll
    for (int nt = 0; nt < 8; ++nt) {
      int col = nwb + nt * 16 + ln;
      unsigned pa = h1p[mt][nt][0], pb = h1p[mt][nt][1];
      float hh[4] = { bfb2f(pa & 0xffffu), bfb2f(pa >> 16),
                      bfb2f(pb & 0xffffu), bfb2f(pb >> 16) };
      #pragma unroll
      for (int r = 0; r < 4; ++r) {
        float gz = acc[mt][nt][r] * (1.0f - hh[r] * hh[r]);
        bufB[(mt * 16 + q * 4 + r) * AST + col] = f2bf(gz);
      }
    }
  __syncthreads();

  // ================ GEMM4: g0 = gz1 @ W1^T ; gz0 = g0*(1-h0^2) ================
  GEMM512(bufB, p1b);
  #pragma unroll
  for (int mt = 0; mt < 2; ++mt)
    #pragma unroll
    for (int nt = 0; nt < 8; ++nt) {
      int col = nwb + nt * 16 + ln;
      unsigned pa = h0p[mt][nt][0], pb = h0p[mt][nt][1];
      float hh[4] = { bfb2f(pa & 0xffffu), bfb2f(pa >> 16),
                      bfb2f(pb & 0xffffu), bfb2f(pb >> 16) };
      #pragma unroll
      for (int r = 0; r < 4; ++r) {
        float gz = acc[mt][nt][r] * (1.0f - hh[r] * hh[r]);
        bufA[(mt * 16 + q * 4 + r) * AST + col] = f2bf(gz);
      }
    }
  __syncthreads();

  // ================ GEMM5: gradH = gz0 @ W0^T (32x64), symplectic store ======
  {
    f32x4 acc5[2];
    acc5[0] = (f32x4){0.f, 0.f, 0.f, 0.f};
    acc5[1] = (f32x4){0.f, 0.f, 0.f, 0.f};
    const int mt5 = wave & 1;            // row half
    const int nb5 = (wave >> 1) * 32;    // gradH column base (0 or 32)
    const u16* bp5 = p0b + ((wave >> 1) << 14) + lane * 8;  // (wave>>1)*2 ntg *16kc*512
    #pragma unroll 2
    for (int kc = 0; kc < 16; ++kc) {
      s16x8 a = *(const s16x8*)(bufA + (mt5 * 16 + ln) * AST + kc * 32 + q * 8);
      #pragma unroll
      for (int nt = 0; nt < 2; ++nt) {
        s16x8 b = *(const s16x8*)(bp5 + ((nt * 16 + kc) << 9));
        acc5[nt] = MFMA_BF16(a, b, acc5[nt]);
      }
    }
    #pragma unroll
    for (int nt = 0; nt < 2; ++nt) {
      int g = nb5 + nt * 16 + ln;                 // gradH column
      int c = (g < 32) ? g + 32 : g - 32;         // out = concat(gradH[:,32:], -gradH[:,:32])
      float s = (g < 32) ? -1.0f : 1.0f;
      #pragma unroll
      for (int r = 0; r < 4; ++r) {
        int grow = row0 + mt5 * 16 + q * 4 + r;
        out[(size_t)grow * 64 + c] = s * acc5[nt][r];
      }
    }
  }
}

extern "C" void kernel_launch(void* const* d_in, const int* in_sizes, int n_in,
                              void* d_out, int out_size, void* d_ws, size_t ws_size,
                              hipStream_t stream) {
  // setup_inputs order: t, x, W0, b0, W1, b1, W2, b2, W3, b3
  const float* x  = (const float*)d_in[1];
  const float* W0 = (const float*)d_in[2];
  const float* b0 = (const float*)d_in[3];
  const float* W1 = (const float*)d_in[4];
  const float* b1 = (const float*)d_in[5];
  const float* W2 = (const float*)d_in[6];
  const float* b2 = (const float*)d_in[7];
  const float* W3 = (const float*)d_in[8];
  u16* ws = (u16*)d_ws;
  float* out = (float*)d_out;

  prep_weights<<<128, 256, 0, stream>>>(W0, W1, W2, ws);
  hnn_fused<<<65536 / M_TILE, 256, 0, stream>>>(x, b0, b1, b2, W3, ws, out);
}